// Round 10
// baseline (2846.073 us; speedup 1.0000x reference)
//
#include <hip/hip_runtime.h>
#include <hip/hip_bf16.h>

#define DD 128   // embedding dim (fixed by problem)
#define RPB 256  // rows per coarse bin

using short8 = __attribute__((ext_vector_type(8))) short;
using f32x4  = __attribute__((ext_vector_type(4))) float;

__device__ inline ushort f2bf(float f) {
    uint u = __builtin_bit_cast(uint, f);
    uint r = (u + 0x7FFFu + ((u >> 16) & 1u)) >> 16;
    return (ushort)r;
}

// ---------------------------------------------------------------------------
// Kernel 1: y2 = bf16(x @ W^T) via MFMA 16x16x32 bf16.  (verified r3/r4 core)
// Epilogue v2: y2 packed layout -- word j of row c holds (dim j, dim j+64):
//   y2[c*64 + j] = bf16(y[c][j]) | bf16(y[c][j+64]) << 16
// Sole consumer is bin_gather (lane l owns dims l and l+64).
// ---------------------------------------------------------------------------
__global__ __launch_bounds__(256) void gemm_mfma(const float* __restrict__ x,
                                                 const float* __restrict__ W,
                                                 uint* __restrict__ y2, int Nr) {
    __shared__ ushort Wl[128 * 136];
    const int t = threadIdx.x;
    const int lane = t & 63;
    const int w = t >> 6;

    for (int i = t; i < 4096; i += 256) {
        float4 w4 = ((const float4*)W)[i];
        int row = i >> 5;
        int k4  = i & 31;
        uint2 p;
        p.x = (uint)f2bf(w4.x) | ((uint)f2bf(w4.y) << 16);
        p.y = (uint)f2bf(w4.z) | ((uint)f2bf(w4.w) << 16);
        *(uint2*)&Wl[row * 136 + k4 * 4] = p;
    }
    __syncthreads();

    const int rbase = blockIdx.x * 128 + w * 32;
    const int lr = lane & 15;
    const int lk = (lane >> 4) * 8;

    f32x4 acc[2][8];
#pragma unroll
    for (int g = 0; g < 2; ++g)
#pragma unroll
        for (int f = 0; f < 8; ++f) acc[g][f] = (f32x4){0.f, 0.f, 0.f, 0.f};

#pragma unroll
    for (int c = 0; c < 4; ++c) {
        const int k0 = c * 32 + lk;
        short8 a[2];
#pragma unroll
        for (int g = 0; g < 2; ++g) {
            long rr = rbase + g * 16 + lr;
            if (rr >= Nr) rr = Nr - 1;
            const float4* xp = (const float4*)&x[(size_t)rr * DD + k0];
            float4 v0 = xp[0];
            float4 v1 = xp[1];
            a[g][0] = (short)f2bf(v0.x); a[g][1] = (short)f2bf(v0.y);
            a[g][2] = (short)f2bf(v0.z); a[g][3] = (short)f2bf(v0.w);
            a[g][4] = (short)f2bf(v1.x); a[g][5] = (short)f2bf(v1.y);
            a[g][6] = (short)f2bf(v1.z); a[g][7] = (short)f2bf(v1.w);
        }
        short8 b[8];
#pragma unroll
        for (int f = 0; f < 8; ++f)
            b[f] = *(const short8*)&Wl[(16 * f + lr) * 136 + k0];
#pragma unroll
        for (int g = 0; g < 2; ++g)
#pragma unroll
            for (int f = 0; f < 8; ++f)
                acc[g][f] = __builtin_amdgcn_mfma_f32_16x16x32_bf16(a[g], b[f], acc[g][f], 0, 0, 0);
    }

    __syncthreads();
#pragma unroll
    for (int g = 0; g < 2; ++g)
#pragma unroll
        for (int f = 0; f < 8; ++f) {
#pragma unroll
            for (int j = 0; j < 4; ++j) {
                int row = w * 32 + g * 16 + (lane >> 4) * 4 + j;
                int col = 16 * f + lr;
                Wl[row * 136 + col] = f2bf(acc[g][f][j]);
            }
        }
    __syncthreads();

    // epilogue v2: paired pack (dim j | dim j+64 << 16)
    const int r = t >> 1, h = t & 1;
    const long gr = (long)blockIdx.x * 128 + r;
    if (gr < Nr) {
        uint4* dst = (uint4*)&y2[(size_t)gr * 64 + h * 32];
#pragma unroll
        for (int q = 0; q < 4; ++q) {
            short8 lov = *(const short8*)&Wl[r * 136 + h * 32 + q * 8];
            short8 hiv = *(const short8*)&Wl[r * 136 + 64 + h * 32 + q * 8];
            uint4 o0, o1;
            o0.x = (uint)(ushort)lov[0] | ((uint)(ushort)hiv[0] << 16);
            o0.y = (uint)(ushort)lov[1] | ((uint)(ushort)hiv[1] << 16);
            o0.z = (uint)(ushort)lov[2] | ((uint)(ushort)hiv[2] << 16);
            o0.w = (uint)(ushort)lov[3] | ((uint)(ushort)hiv[3] << 16);
            o1.x = (uint)(ushort)lov[4] | ((uint)(ushort)hiv[4] << 16);
            o1.y = (uint)(ushort)lov[5] | ((uint)(ushort)hiv[5] << 16);
            o1.z = (uint)(ushort)lov[6] | ((uint)(ushort)hiv[6] << 16);
            o1.w = (uint)(ushort)lov[7] | ((uint)(ushort)hiv[7] << 16);
            dst[q * 2]     = o0;
            dst[q * 2 + 1] = o1;
        }
    }
}

// ---------------------------------------------------------------------------
// bin_hist: per-block LDS histogram of row bins.  (verified r3/r4)
// ---------------------------------------------------------------------------
__global__ __launch_bounds__(512) void bin_hist(const int4* __restrict__ er4,
                                                int* __restrict__ binCnt,
                                                int E4, int nbins) {
    __shared__ int h[1024];
    const int t = threadIdx.x;
    for (int i = t; i < nbins; i += 512) h[i] = 0;
    __syncthreads();
    const int base = blockIdx.x * 2048;           // 2048 int4 = 8192 edges
    const int lim = min(base + 2048, E4);
    for (int i = base + t; i < lim; i += 512) {
        int4 e = er4[i];
        atomicAdd(&h[e.x >> 8], 1);
        atomicAdd(&h[e.y >> 8], 1);
        atomicAdd(&h[e.z >> 8], 1);
        atomicAdd(&h[e.w >> 8], 1);
    }
    __syncthreads();
    for (int i = t; i < nbins; i += 512)
        if (h[i]) atomicAdd(&binCnt[i], h[i]);
}

// ---------------------------------------------------------------------------
// bin_scan: single-block scan of bin counts -> binBase/binCursor. (verified)
// ---------------------------------------------------------------------------
__global__ __launch_bounds__(1024) void bin_scan(const int* __restrict__ binCnt,
                                                 int* __restrict__ binBase,
                                                 int* __restrict__ binCursor,
                                                 int nbins, int E) {
    __shared__ int part[1024];
    const int t = threadIdx.x;
    int v = (t < nbins) ? binCnt[t] : 0;
    part[t] = v;
    __syncthreads();
    for (int off = 1; off < 1024; off <<= 1) {
        int u = (t >= off) ? part[t - off] : 0;
        __syncthreads();
        part[t] += u;
        __syncthreads();
    }
    if (t < nbins) {
        int b = part[t] - v;
        binBase[t] = b;
        binCursor[t] = b;
    }
    if (t == 0) binBase[nbins] = E;
}

// ---------------------------------------------------------------------------
// bin_scatter: partition edges into CSR bin regions of brec (in d_out).
// (verified r3/r4; rec.x = col | rowlow<<18)
// ---------------------------------------------------------------------------
__global__ __launch_bounds__(512) void bin_scatter(const int* __restrict__ er,
                                                   const int* __restrict__ ec,
                                                   const float* __restrict__ ev,
                                                   int* __restrict__ binCursor,
                                                   uint2* __restrict__ brec,
                                                   int E4, int nbins) {
    __shared__ int h[1024];
    __shared__ int base[1024];
    const int t = threadIdx.x;
    for (int i = t; i < nbins; i += 512) h[i] = 0;
    __syncthreads();

    const int b4 = blockIdx.x * 2048;             // int4 base index
    int rows[16];
#pragma unroll
    for (int j = 0; j < 4; ++j) {
        int i4 = b4 + j * 512 + t;
        if (i4 < E4) {
            int4 e = ((const int4*)er)[i4];
            rows[j * 4 + 0] = e.x; rows[j * 4 + 1] = e.y;
            rows[j * 4 + 2] = e.z; rows[j * 4 + 3] = e.w;
            atomicAdd(&h[e.x >> 8], 1);
            atomicAdd(&h[e.y >> 8], 1);
            atomicAdd(&h[e.z >> 8], 1);
            atomicAdd(&h[e.w >> 8], 1);
        }
    }
    __syncthreads();
    for (int i = t; i < nbins; i += 512) {
        int c = h[i];
        base[i] = c ? atomicAdd(&binCursor[i], c) : 0;
        h[i] = 0;
    }
    __syncthreads();
#pragma unroll
    for (int j = 0; j < 4; ++j) {
        int i4 = b4 + j * 512 + t;
        if (i4 < E4) {
            int4 c4 = ((const int4*)ec)[i4];
            float4 v4 = ((const float4*)ev)[i4];
            int cs[4] = {c4.x, c4.y, c4.z, c4.w};
            float vs[4] = {v4.x, v4.y, v4.z, v4.w};
#pragma unroll
            for (int k = 0; k < 4; ++k) {
                int row = rows[j * 4 + k];
                int bin = row >> 8;
                int li = atomicAdd(&h[bin], 1);
                uint2 rec;
                rec.x = (uint)cs[k] | ((uint)(row & 255) << 18);
                rec.y = __builtin_bit_cast(uint, vs[k]);
                brec[base[bin] + li] = rec;
            }
        }
    }
}

// ---------------------------------------------------------------------------
// fine_scatter v2: per-bin COLUMN sort (key = col>>8, 9 bits) -> recs.
// Same verified hist/scan/scatter machinery as r3/r4, key swapped and the
// full rec (rowlow + col) preserved for the accumulating gather.
// ---------------------------------------------------------------------------
__global__ __launch_bounds__(512) void fine_scatter(const uint2* __restrict__ brec,
                                                    const int* __restrict__ binBase,
                                                    uint2* __restrict__ recs) {
    __shared__ int h[512], cur[512], p[512];
    const int t = threadIdx.x;
    const int b = blockIdx.x;
    const int s = binBase[b];
    const int cnt = binBase[b + 1] - s;

    h[t] = 0;
    __syncthreads();
    for (int i = t; i < cnt; i += 512) {
        uint k = (brec[s + i].x >> 8) & 0x1FFu;   // col bits 8..16 (col < 2^17)
        atomicAdd(&h[(int)k], 1);
    }
    __syncthreads();
    int v = h[t];
    p[t] = v;
    __syncthreads();
    for (int off = 1; off < 512; off <<= 1) {
        int u = (t >= off) ? p[t - off] : 0;
        __syncthreads();
        p[t] += u;
        __syncthreads();
    }
    cur[t] = p[t] - v;
    __syncthreads();
    for (int i = t; i < cnt; i += 512) {
        uint2 rc = brec[s + i];
        int k = (int)((rc.x >> 8) & 0x1FFu);
        int li = atomicAdd(&cur[k], 1);
        recs[s + li] = rc;                         // keep full rec
    }
}

// ---------------------------------------------------------------------------
// bin_gather: one block per 256-row bin, LDS f32 accumulator (256x132 =
// 132KB, 1 block/CU). Records are col-sorted, so all blocks stream y2 in
// ascending column order -> active y window stays L2/L3-resident (r3-r8
// showed the row-gather is walled at ~3.4 TB/s of RANDOM 256B fetches).
// Each record handled by one full wave: 1 coalesced 256B y2 read (lane l =
// dims l, l+64 packed) + 2 LDS atomicAdd per lane (2-way bank alias, free).
// r9 BUG FIX: record-loop stride was 512 (8x undercount); 8 waves x 8
// records = 64 records per round -> stride 64.
// ---------------------------------------------------------------------------
__global__ __launch_bounds__(512) void bin_gather(const uint2* __restrict__ recs,
                                                  const int* __restrict__ binBase,
                                                  const uint* __restrict__ y2,
                                                  float* __restrict__ out) {
    __shared__ float acc[256 * 132];
    const int t = threadIdx.x;
    const int b = blockIdx.x;
    for (int i = t; i < 256 * 132; i += 512) acc[i] = 0.f;
    __syncthreads();

    const int s = binBase[b];
    const int e = binBase[b + 1];
    const int w = t >> 6;
    const int l = t & 63;

    // wave w handles records s + w*8 + {0..7}, advancing 64 per round
    for (int i = s + w * 8; i < e; i += 64) {
#pragma unroll
        for (int m = 0; m < 8; ++m) {
            const int idx = i + m;
            if (idx < e) {
                const uint2 rc = recs[idx];        // wave-uniform load
                const uint rx = rc.x;
                const float v = __builtin_bit_cast(float, rc.y);
                const int c = (int)(rx & 0x3FFFFu);
                const int rl = (int)(rx >> 18);
                const uint q = y2[(size_t)c * 64 + l];
                const float lo = __builtin_bit_cast(float, q << 16);          // dim l
                const float hi = __builtin_bit_cast(float, q & 0xFFFF0000u);  // dim l+64
                atomicAdd(&acc[rl * 132 + l], v * lo);
                atomicAdd(&acc[rl * 132 + 64 + l], v * hi);
            }
        }
    }
    __syncthreads();

    // coalesced writeback: 256 rows x 128 f32
    const size_t obase = (size_t)b * 256 * 128;
#pragma unroll
    for (int fi = t * 4; fi < 32768; fi += 2048) {
        const int row = fi >> 7;
        const int d = fi & 127;
        f32x4 vv = *(const f32x4*)&acc[row * 132 + d];
        *(f32x4*)&out[obase + (size_t)row * 128 + d] = vv;
    }
}

// ---------------------------------------------------------------------------
// Fallback path (tiny workspace / odd shapes): exact f32, slow.  (verified)
// ---------------------------------------------------------------------------
__global__ void fb_scatter(const int* __restrict__ er, const int* __restrict__ ec,
                           const float* __restrict__ ev, const float* __restrict__ x,
                           float* __restrict__ out, int E) {
    long long idx = (long long)blockIdx.x * 256 + threadIdx.x;
    long long tot = (long long)E * 32;
    if (idx >= tot) return;
    int e = (int)(idx >> 5);
    int q = (int)(idx & 31);
    int r = er[e], c = ec[e];
    float v = ev[e];
    const float4 xv = ((const float4*)&x[(size_t)c * DD])[q];
    float* o = &out[(size_t)r * DD + q * 4];
    atomicAdd(o + 0, v * xv.x);
    atomicAdd(o + 1, v * xv.y);
    atomicAdd(o + 2, v * xv.z);
    atomicAdd(o + 3, v * xv.w);
}

__global__ __launch_bounds__(256) void fb_inplace_gemm(float* __restrict__ out,
                                                       const float* __restrict__ W, int Nn) {
    __shared__ float rowbuf[4][DD];
    const int wave = threadIdx.x >> 6;
    const int lane = threadIdx.x & 63;
    const int row = blockIdx.x * 4 + wave;
    if (row < Nn) {
        float2 pr = ((const float2*)&out[(size_t)row * DD])[lane];
        rowbuf[wave][lane * 2 + 0] = pr.x;
        rowbuf[wave][lane * 2 + 1] = pr.y;
    }
    __syncthreads();
    if (row >= Nn) return;
    const int d0 = lane * 2, d1 = lane * 2 + 1;
    float a0 = 0.f, a1 = 0.f;
    for (int j = 0; j < 32; ++j) {
        float4 xv = *(const float4*)&rowbuf[wave][j * 4];
        float4 w0 = ((const float4*)W)[d0 * 32 + j];
        float4 w1 = ((const float4*)W)[d1 * 32 + j];
        a0 += w0.x * xv.x + w0.y * xv.y + w0.z * xv.z + w0.w * xv.w;
        a1 += w1.x * xv.x + w1.y * xv.y + w1.z * xv.z + w1.w * xv.w;
    }
    float2 o;
    o.x = a0;
    o.y = a1;
    ((float2*)&out[(size_t)row * DD])[lane] = o;
}

// ---------------------------------------------------------------------------
extern "C" void kernel_launch(void* const* d_in, const int* in_sizes, int n_in,
                              void* d_out, int out_size, void* d_ws, size_t ws_size,
                              hipStream_t stream) {
    const float* x  = (const float*)d_in[0];
    const int*   er = (const int*)d_in[1];
    const int*   ec = (const int*)d_in[2];
    const float* ev = (const float*)d_in[3];
    const float* W  = (const float*)d_in[4];
    float* out = (float*)d_out;

    const int Nn = in_sizes[0] / DD;   // 131072
    const int E  = in_sizes[1];        // 4194304
    const int nbins = Nn >> 8;         // 512 for the bench shape

    // workspace layout
    size_t off = 0;
    auto align256 = [](size_t v) { return (v + 255) & ~(size_t)255; };
    size_t y_off = off;        off = align256(off + (size_t)Nn * DD * 2);      // packed y2
    size_t recs_off = off;     off = align256(off + (size_t)E * 8);            // sorted recs
    size_t cnt_off = off;      off = align256(off + (size_t)nbins * 4);
    size_t base_off = off;     off = align256(off + ((size_t)nbins + 1) * 4);
    size_t cur_off = off;      off = align256(off + (size_t)nbins * 4);
    size_t need = off;

    char* ws = (char*)d_ws;

    // d_out must hold Nn*DD floats by contract => Nn*DD*4 bytes of scratch.
    // nbins <= 512 required for the 9-bit col-bin sort key.
    const bool main_ok = ws_size >= need && (Nn & 255) == 0 && nbins >= 1 &&
                         nbins <= 512 && (E & 3) == 0 &&
                         (size_t)E * 8 <= (size_t)Nn * DD * 4;

    if (main_ok) {
        uint* y2       = (uint*)(ws + y_off);
        uint2* recs    = (uint2*)(ws + recs_off);
        int* binCnt    = (int*)(ws + cnt_off);
        int* binBase   = (int*)(ws + base_off);
        int* binCursor = (int*)(ws + cur_off);
        uint2* brec    = (uint2*)d_out;   // d_out doubles as binned-record scratch

        const int E4 = E / 4;
        const int nblk = (E4 + 2047) / 2048;   // 8192 edges per block

        gemm_mfma<<<(Nn + 127) / 128, 256, 0, stream>>>(x, W, y2, Nn);

        (void)hipMemsetAsync(binCnt, 0, (size_t)nbins * 4, stream);
        bin_hist<<<nblk, 512, 0, stream>>>((const int4*)er, binCnt, E4, nbins);
        bin_scan<<<1, 1024, 0, stream>>>(binCnt, binBase, binCursor, nbins, E);
        bin_scatter<<<nblk, 512, 0, stream>>>(er, ec, ev, binCursor, brec, E4, nbins);
        fine_scatter<<<nbins, 512, 0, stream>>>(brec, binBase, recs);
        bin_gather<<<nbins, 512, 0, stream>>>(recs, binBase, y2, out);
    } else {
        // fallback: atomics into d_out, then in-place row-wise GEMM
        (void)hipMemsetAsync(out, 0, (size_t)Nn * DD * 4, stream);
        long long tot = (long long)E * 32;
        int blocks = (int)((tot + 255) / 256);
        fb_scatter<<<blocks, 256, 0, stream>>>(er, ec, ev, x, out, E);
        fb_inplace_gemm<<<(Nn + 3) / 4, 256, 0, stream>>>(out, W, Nn);
    }
}

// Round 11
// 263.541 us; speedup vs baseline: 10.7994x; 10.7994x over previous
//
#include <hip/hip_runtime.h>
#include <hip/hip_bf16.h>

#define DD 128   // embedding dim (fixed by problem)
#define RPB 256  // rows per coarse bin

using short8 = __attribute__((ext_vector_type(8))) short;
using f32x4  = __attribute__((ext_vector_type(4))) float;

__device__ inline ushort f2bf(float f) {
    uint u = __builtin_bit_cast(uint, f);
    uint r = (u + 0x7FFFu + ((u >> 16) & 1u)) >> 16;
    return (ushort)r;
}

// ---------------------------------------------------------------------------
// Kernel 1: y_bf16 = bf16(x @ W^T) via MFMA 16x16x32 bf16.  (verified r3)
// ---------------------------------------------------------------------------
__global__ __launch_bounds__(256) void gemm_mfma(const float* __restrict__ x,
                                                 const float* __restrict__ W,
                                                 ushort* __restrict__ y, int Nr) {
    __shared__ ushort Wl[128 * 136];
    const int t = threadIdx.x;
    const int lane = t & 63;
    const int w = t >> 6;

    for (int i = t; i < 4096; i += 256) {
        float4 w4 = ((const float4*)W)[i];
        int row = i >> 5;
        int k4  = i & 31;
        uint2 p;
        p.x = (uint)f2bf(w4.x) | ((uint)f2bf(w4.y) << 16);
        p.y = (uint)f2bf(w4.z) | ((uint)f2bf(w4.w) << 16);
        *(uint2*)&Wl[row * 136 + k4 * 4] = p;
    }
    __syncthreads();

    const int rbase = blockIdx.x * 128 + w * 32;
    const int lr = lane & 15;
    const int lk = (lane >> 4) * 8;

    f32x4 acc[2][8];
#pragma unroll
    for (int g = 0; g < 2; ++g)
#pragma unroll
        for (int f = 0; f < 8; ++f) acc[g][f] = (f32x4){0.f, 0.f, 0.f, 0.f};

#pragma unroll
    for (int c = 0; c < 4; ++c) {
        const int k0 = c * 32 + lk;
        short8 a[2];
#pragma unroll
        for (int g = 0; g < 2; ++g) {
            long rr = rbase + g * 16 + lr;
            if (rr >= Nr) rr = Nr - 1;
            const float4* xp = (const float4*)&x[(size_t)rr * DD + k0];
            float4 v0 = xp[0];
            float4 v1 = xp[1];
            a[g][0] = (short)f2bf(v0.x); a[g][1] = (short)f2bf(v0.y);
            a[g][2] = (short)f2bf(v0.z); a[g][3] = (short)f2bf(v0.w);
            a[g][4] = (short)f2bf(v1.x); a[g][5] = (short)f2bf(v1.y);
            a[g][6] = (short)f2bf(v1.z); a[g][7] = (short)f2bf(v1.w);
        }
        short8 b[8];
#pragma unroll
        for (int f = 0; f < 8; ++f)
            b[f] = *(const short8*)&Wl[(16 * f + lr) * 136 + k0];
#pragma unroll
        for (int g = 0; g < 2; ++g)
#pragma unroll
            for (int f = 0; f < 8; ++f)
                acc[g][f] = __builtin_amdgcn_mfma_f32_16x16x32_bf16(a[g], b[f], acc[g][f], 0, 0, 0);
    }

    __syncthreads();
#pragma unroll
    for (int g = 0; g < 2; ++g)
#pragma unroll
        for (int f = 0; f < 8; ++f) {
#pragma unroll
            for (int j = 0; j < 4; ++j) {
                int row = w * 32 + g * 16 + (lane >> 4) * 4 + j;
                int col = 16 * f + lr;
                Wl[row * 136 + col] = f2bf(acc[g][f][j]);
            }
        }
    __syncthreads();

    const int r = t >> 1, h = t & 1;
    const long gr = (long)blockIdx.x * 128 + r;
    if (gr < Nr) {
        const int4* src = (const int4*)&Wl[r * 136 + h * 64];
        int4* dst = (int4*)&y[(size_t)gr * DD + h * 64];
#pragma unroll
        for (int i = 0; i < 8; ++i) dst[i] = src[i];
    }
}

// ---------------------------------------------------------------------------
// Two-level CSR build.  (verified r3)
// ---------------------------------------------------------------------------
__global__ __launch_bounds__(512) void bin_hist(const int4* __restrict__ er4,
                                                int* __restrict__ binCnt,
                                                int E4, int nbins) {
    __shared__ int h[1024];
    const int t = threadIdx.x;
    for (int i = t; i < nbins; i += 512) h[i] = 0;
    __syncthreads();
    const int base = blockIdx.x * 2048;           // 2048 int4 = 8192 edges
    const int lim = min(base + 2048, E4);
    for (int i = base + t; i < lim; i += 512) {
        int4 e = er4[i];
        atomicAdd(&h[e.x >> 8], 1);
        atomicAdd(&h[e.y >> 8], 1);
        atomicAdd(&h[e.z >> 8], 1);
        atomicAdd(&h[e.w >> 8], 1);
    }
    __syncthreads();
    for (int i = t; i < nbins; i += 512)
        if (h[i]) atomicAdd(&binCnt[i], h[i]);
}

__global__ __launch_bounds__(1024) void bin_scan(const int* __restrict__ binCnt,
                                                 int* __restrict__ binBase,
                                                 int* __restrict__ binCursor,
                                                 int* __restrict__ offsets,
                                                 int nbins, int Nn, int E) {
    __shared__ int part[1024];
    const int t = threadIdx.x;
    int v = (t < nbins) ? binCnt[t] : 0;
    part[t] = v;
    __syncthreads();
    for (int off = 1; off < 1024; off <<= 1) {
        int u = (t >= off) ? part[t - off] : 0;
        __syncthreads();
        part[t] += u;
        __syncthreads();
    }
    if (t < nbins) {
        int b = part[t] - v;
        binBase[t] = b;
        binCursor[t] = b;
    }
    if (t == 0) {
        binBase[nbins] = E;
        offsets[Nn] = E;
    }
}

__global__ __launch_bounds__(512) void bin_scatter(const int* __restrict__ er,
                                                   const int* __restrict__ ec,
                                                   const float* __restrict__ ev,
                                                   int* __restrict__ binCursor,
                                                   uint2* __restrict__ brec,
                                                   int E4, int nbins) {
    __shared__ int h[1024];
    __shared__ int base[1024];
    const int t = threadIdx.x;
    for (int i = t; i < nbins; i += 512) h[i] = 0;
    __syncthreads();

    const int b4 = blockIdx.x * 2048;             // int4 base index
    int rows[16];
    // phase a: local histogram, keep rows in regs
#pragma unroll
    for (int j = 0; j < 4; ++j) {
        int i4 = b4 + j * 512 + t;
        if (i4 < E4) {
            int4 e = ((const int4*)er)[i4];
            rows[j * 4 + 0] = e.x; rows[j * 4 + 1] = e.y;
            rows[j * 4 + 2] = e.z; rows[j * 4 + 3] = e.w;
            atomicAdd(&h[e.x >> 8], 1);
            atomicAdd(&h[e.y >> 8], 1);
            atomicAdd(&h[e.z >> 8], 1);
            atomicAdd(&h[e.w >> 8], 1);
        }
    }
    __syncthreads();
    // phase b: reserve a contiguous run per bin, reset local cursors
    for (int i = t; i < nbins; i += 512) {
        int c = h[i];
        base[i] = c ? atomicAdd(&binCursor[i], c) : 0;
        h[i] = 0;
    }
    __syncthreads();
    // phase c: scatter packed records
#pragma unroll
    for (int j = 0; j < 4; ++j) {
        int i4 = b4 + j * 512 + t;
        if (i4 < E4) {
            int4 c4 = ((const int4*)ec)[i4];
            float4 v4 = ((const float4*)ev)[i4];
            int cs[4] = {c4.x, c4.y, c4.z, c4.w};
            float vs[4] = {v4.x, v4.y, v4.z, v4.w};
#pragma unroll
            for (int k = 0; k < 4; ++k) {
                int row = rows[j * 4 + k];
                int bin = row >> 8;
                int li = atomicAdd(&h[bin], 1);
                uint2 rec;
                rec.x = (uint)cs[k] | ((uint)(row & 255) << 18);
                rec.y = __builtin_bit_cast(uint, vs[k]);
                brec[base[bin] + li] = rec;
            }
        }
    }
}

__global__ __launch_bounds__(512) void fine_scatter(const uint2* __restrict__ brec,
                                                    const int* __restrict__ binBase,
                                                    int* __restrict__ offsets,
                                                    uint2* __restrict__ recs) {
    __shared__ int h[RPB];
    __shared__ int cur[RPB];
    __shared__ int p[RPB];
    const int t = threadIdx.x;
    const int b = blockIdx.x;
    const int s = binBase[b];
    const int cnt = binBase[b + 1] - s;

    if (t < RPB) h[t] = 0;
    __syncthreads();
    for (int i = t; i < cnt; i += 512) {
        uint r = brec[s + i].x >> 18;
        atomicAdd(&h[(int)r], 1);
    }
    __syncthreads();
    int vv = (t < RPB) ? h[t] : 0;
    if (t < RPB) p[t] = vv;
    __syncthreads();
    for (int off = 1; off < RPB; off <<= 1) {
        int u = (t < RPB && t >= off) ? p[t - off] : 0;
        __syncthreads();
        if (t < RPB) p[t] += u;
        __syncthreads();
    }
    if (t < RPB) {
        int excl = p[t] - vv;
        cur[t] = excl;
        offsets[b * RPB + t] = s + excl;
    }
    __syncthreads();
    for (int i = t; i < cnt; i += 512) {
        uint2 rc = brec[s + i];
        int r = (int)(rc.x >> 18);
        int li = atomicAdd(&cur[r], 1);
        uint2 outrec;
        outrec.x = rc.x & 0x3FFFFu;
        outrec.y = rc.y;
        recs[s + li] = outrec;
    }
}

// ---------------------------------------------------------------------------
// Gather: one wave per output row, 4 edges in flight per wave.  (verified r3,
// 144 us: random-256B-segment throughput wall of the L2/L3 hierarchy --
// 1.07 GB logical at ~7.4 TB/s effective; MLP-insensitive per r4 A/B.)
// ---------------------------------------------------------------------------
__global__ __launch_bounds__(256) void gather_kernel(const ushort* __restrict__ y,
                                                     const int* __restrict__ offsets,
                                                     const uint2* __restrict__ recs,
                                                     float* __restrict__ out, int Nn) {
    const int wave = threadIdx.x >> 6;
    const int lane = threadIdx.x & 63;
    const int row = blockIdx.x * 4 + wave;
    if (row >= Nn) return;
    const int start = offsets[row];
    const int end = offsets[row + 1];
    const int g = lane >> 4;        // which of 4 concurrent edges
    const int c16 = lane & 15;      // 8-col slice within the row

    float acc[8];
#pragma unroll
    for (int k = 0; k < 8; ++k) acc[k] = 0.f;

    for (int b = start; b < end; b += 64) {
        const int n = min(64, end - b);
        int mc = 0;
        float mv = 0.f;
        if (lane < n) {
            uint2 rec = recs[b + lane];
            mc = (int)rec.x;
            mv = __builtin_bit_cast(float, rec.y);
        }
        const int niter = (n + 3) >> 2;
#pragma unroll 2
        for (int i = 0; i < niter; ++i) {
            const int idx = i * 4 + g;              // < 64 always
            int c = __shfl(mc, idx);                // idx >= n -> v == 0
            float v = __shfl(mv, idx);
            uint4 q = *(const uint4*)&y[(size_t)c * DD + c16 * 8];
            uint p0 = q.x, p1 = q.y, p2 = q.z, p3 = q.w;
            acc[0] += v * __builtin_bit_cast(float, p0 << 16);
            acc[1] += v * __builtin_bit_cast(float, p0 & 0xFFFF0000u);
            acc[2] += v * __builtin_bit_cast(float, p1 << 16);
            acc[3] += v * __builtin_bit_cast(float, p1 & 0xFFFF0000u);
            acc[4] += v * __builtin_bit_cast(float, p2 << 16);
            acc[5] += v * __builtin_bit_cast(float, p2 & 0xFFFF0000u);
            acc[6] += v * __builtin_bit_cast(float, p3 << 16);
            acc[7] += v * __builtin_bit_cast(float, p3 & 0xFFFF0000u);
        }
    }

    // reduce the 4 edge-groups' partials (lanes l, l^16, l^32, l^48)
#pragma unroll
    for (int k = 0; k < 8; ++k) {
        acc[k] += __shfl_xor(acc[k], 16);
        acc[k] += __shfl_xor(acc[k], 32);
    }

    // each lane stores 8B: cols c16*8 + g*2 + {0,1}
    float2 o;
    o.x = acc[g * 2];
    o.y = acc[g * 2 + 1];
    ((float2*)out)[(size_t)row * 64 + c16 * 4 + g] = o;
}

// ---------------------------------------------------------------------------
// Fallback path (tiny workspace): exact f32, slow.  (verified r1)
// ---------------------------------------------------------------------------
__global__ void fb_scatter(const int* __restrict__ er, const int* __restrict__ ec,
                           const float* __restrict__ ev, const float* __restrict__ x,
                           float* __restrict__ out, int E) {
    long long idx = (long long)blockIdx.x * 256 + threadIdx.x;
    long long tot = (long long)E * 32;
    if (idx >= tot) return;
    int e = (int)(idx >> 5);
    int q = (int)(idx & 31);
    int r = er[e], c = ec[e];
    float v = ev[e];
    const float4 xv = ((const float4*)&x[(size_t)c * DD])[q];
    float* o = &out[(size_t)r * DD + q * 4];
    atomicAdd(o + 0, v * xv.x);
    atomicAdd(o + 1, v * xv.y);
    atomicAdd(o + 2, v * xv.z);
    atomicAdd(o + 3, v * xv.w);
}

__global__ __launch_bounds__(256) void fb_inplace_gemm(float* __restrict__ out,
                                                       const float* __restrict__ W, int Nn) {
    __shared__ float rowbuf[4][DD];
    const int wave = threadIdx.x >> 6;
    const int lane = threadIdx.x & 63;
    const int row = blockIdx.x * 4 + wave;
    if (row < Nn) {
        float2 pr = ((const float2*)&out[(size_t)row * DD])[lane];
        rowbuf[wave][lane * 2 + 0] = pr.x;
        rowbuf[wave][lane * 2 + 1] = pr.y;
    }
    __syncthreads();
    if (row >= Nn) return;
    const int d0 = lane * 2, d1 = lane * 2 + 1;
    float a0 = 0.f, a1 = 0.f;
    for (int j = 0; j < 32; ++j) {
        float4 xv = *(const float4*)&rowbuf[wave][j * 4];
        float4 w0 = ((const float4*)W)[d0 * 32 + j];
        float4 w1 = ((const float4*)W)[d1 * 32 + j];
        a0 += w0.x * xv.x + w0.y * xv.y + w0.z * xv.z + w0.w * xv.w;
        a1 += w1.x * xv.x + w1.y * xv.y + w1.z * xv.z + w1.w * xv.w;
    }
    float2 o;
    o.x = a0;
    o.y = a1;
    ((float2*)&out[(size_t)row * DD])[lane] = o;
}

// ---------------------------------------------------------------------------
extern "C" void kernel_launch(void* const* d_in, const int* in_sizes, int n_in,
                              void* d_out, int out_size, void* d_ws, size_t ws_size,
                              hipStream_t stream) {
    const float* x  = (const float*)d_in[0];
    const int*   er = (const int*)d_in[1];
    const int*   ec = (const int*)d_in[2];
    const float* ev = (const float*)d_in[3];
    const float* W  = (const float*)d_in[4];
    float* out = (float*)d_out;

    const int Nn = in_sizes[0] / DD;   // 131072
    const int E  = in_sizes[1];        // 4194304
    const int nbins = Nn >> 8;         // 512 for the bench shape

    // workspace layout
    size_t off = 0;
    auto align256 = [](size_t v) { return (v + 255) & ~(size_t)255; };
    size_t y_off = off;        off = align256(off + (size_t)Nn * DD * 2);      // bf16 y
    size_t recs_off = off;     off = align256(off + (size_t)E * 8);            // (col,val)
    size_t cnt_off = off;      off = align256(off + (size_t)nbins * 4);
    size_t base_off = off;     off = align256(off + ((size_t)nbins + 1) * 4);
    size_t cur_off = off;      off = align256(off + (size_t)nbins * 4);
    size_t offsets_off = off;  off = align256(off + ((size_t)Nn + 1) * 4);
    size_t need = off;

    char* ws = (char*)d_ws;

    // d_out must hold Nn*DD floats by contract => Nn*DD*4 bytes of scratch.
    const bool main_ok = ws_size >= need && (Nn & 255) == 0 && nbins >= 1 &&
                         nbins <= 1024 && (E & 3) == 0 &&
                         (size_t)E * 8 <= (size_t)Nn * DD * 4;

    if (main_ok) {
        ushort* y      = (ushort*)(ws + y_off);
        uint2* recs    = (uint2*)(ws + recs_off);
        int* binCnt    = (int*)(ws + cnt_off);
        int* binBase   = (int*)(ws + base_off);
        int* binCursor = (int*)(ws + cur_off);
        int* offsets   = (int*)(ws + offsets_off);
        uint2* brec    = (uint2*)d_out;   // d_out doubles as binned-record scratch

        const int E4 = E / 4;
        const int nblk = (E4 + 2047) / 2048;   // 8192 edges per block

        gemm_mfma<<<(Nn + 127) / 128, 256, 0, stream>>>(x, W, y, Nn);

        (void)hipMemsetAsync(binCnt, 0, (size_t)nbins * 4, stream);
        bin_hist<<<nblk, 512, 0, stream>>>((const int4*)er, binCnt, E4, nbins);
        bin_scan<<<1, 1024, 0, stream>>>(binCnt, binBase, binCursor, offsets, nbins, Nn, E);
        bin_scatter<<<nblk, 512, 0, stream>>>(er, ec, ev, binCursor, brec, E4, nbins);
        fine_scatter<<<nbins, 512, 0, stream>>>(brec, binBase, offsets, recs);
        gather_kernel<<<(Nn + 3) / 4, 256, 0, stream>>>(y, offsets, recs, out, Nn);
    } else {
        // fallback: atomics into d_out, then in-place row-wise GEMM
        (void)hipMemsetAsync(out, 0, (size_t)Nn * DD * 4, stream);
        long long tot = (long long)E * 32;
        int blocks = (int)((tot + 255) / 256);
        fb_scatter<<<blocks, 256, 0, stream>>>(er, ec, ev, x, out, E);
        fb_inplace_gemm<<<(Nn + 3) / 4, 256, 0, stream>>>(out, W, Nn);
    }
}